// Round 1
// baseline (101.658 us; speedup 1.0000x reference)
//
#include <hip/hip_runtime.h>

// ---- problem constants ----
#define T_TOK 2048
#define HID   1024
#define INTER_ 1024
#define NEXP  8
#define NPAIR 4096      // TOKENS * TOPK
#define PERM_MAX 4608   // 4096 + 8*64 worst-case padding

typedef unsigned short u16;
typedef __attribute__((ext_vector_type(8))) short bf16x8;
typedef __attribute__((ext_vector_type(4))) float f32x4;
typedef __attribute__((ext_vector_type(4))) unsigned short us4;
typedef __attribute__((ext_vector_type(4))) unsigned int u32x4;

static __device__ __forceinline__ u16 f2bf(float f) {
  union { float f; unsigned u; } v; v.f = f;
  unsigned u = v.u;
  unsigned r = (u + 0x7fffu + ((u >> 16) & 1u)) >> 16;
  return (u16)r;
}

// ---- prep: zero d_out, convert x -> bf16 ----
__global__ __launch_bounds__(256) void k_prep(const float* __restrict__ x,
                                              u16* __restrict__ xb,
                                              float* __restrict__ out) {
  int i = blockIdx.x * 256 + threadIdx.x;   // 1024 blocks -> 262144 threads * 8 elems = 2M
  int base = i * 8;
  f32x4 v0 = *(const f32x4*)(x + base);
  f32x4 v1 = *(const f32x4*)(x + base + 4);
  us4 a = { f2bf(v0[0]), f2bf(v0[1]), f2bf(v0[2]), f2bf(v0[3]) };
  us4 b = { f2bf(v1[0]), f2bf(v1[1]), f2bf(v1[2]), f2bf(v1[3]) };
  *(us4*)(xb + base)     = a;
  *(us4*)(xb + base + 4) = b;
  f32x4 z = {0.f, 0.f, 0.f, 0.f};
  *(f32x4*)(out + base)     = z;
  *(f32x4*)(out + base + 4) = z;
}

// ---- routing: counts -> padded segment bases -> permutation ----
__global__ __launch_bounds__(256) void k_route(const int* __restrict__ sel,
                                               int* __restrict__ hdr,   // seg_base[9]
                                               int* __restrict__ perm) {
  __shared__ int cnt[NEXP];
  __shared__ int cur[NEXP];
  int tid = threadIdx.x;
  if (tid < NEXP) cnt[tid] = 0;
  __syncthreads();
  for (int p = tid; p < NPAIR; p += 256) atomicAdd(&cnt[sel[p]], 1);
  __syncthreads();
  if (tid == 0) {
    int acc = 0;
    for (int e = 0; e < NEXP; e++) {
      hdr[e] = acc;
      cur[e] = acc;
      acc += (cnt[e] + 63) & ~63;   // pad each segment to 64
    }
    hdr[NEXP] = acc;
  }
  __syncthreads();
  for (int i = tid; i < PERM_MAX; i += 256) perm[i] = -1;
  __syncthreads();
  for (int p = tid; p < NPAIR; p += 256) {
    int e = sel[p];
    int slot = atomicAdd(&cur[e], 1);
    perm[slot] = p;
  }
}

// ---- GEMM 1: gate + up, fused SwiGLU, h (bf16) out ----
// tile 64(M) x 64(N), BK=64, 4 waves each computing a 32x32 quadrant
__global__ __launch_bounds__(256) void k_gateup(const u16* __restrict__ xb,
                                                const float* __restrict__ gw,
                                                const float* __restrict__ uw,
                                                const int* __restrict__ hdr,
                                                const int* __restrict__ perm,
                                                u16* __restrict__ hbuf) {
  __shared__ __align__(16) u16 lA[4096];
  __shared__ __align__(16) u16 lBg[4096];
  __shared__ __align__(16) u16 lBu[4096];

  const int tid = threadIdx.x;
  const int lane = tid & 63;
  const int wv = tid >> 6;
  const int n0 = blockIdx.x * 64;
  const int m0 = blockIdx.y * 64;
  const int total = hdr[NEXP];
  if (m0 >= total) return;
  int e = 0;
  #pragma unroll
  for (int k = 1; k < NEXP; k++) if (m0 >= hdr[k]) e = k;

  // A staging: 512 chunks of 16B (8 bf16). chunk c: row r=c>>3, slot q=c&7.
  // LDS[r][q^(r&7)] = global[r][q]  (XOR swizzle on 16B slots)
  const int c0 = tid, c1 = 256 + tid;
  const int r0 = c0 >> 3, q0 = c0 & 7;
  const int r1 = c1 >> 3, q1 = c1 & 7;
  const int p0 = perm[m0 + r0]; const int tok0 = (p0 < 0) ? 0 : (p0 >> 1);
  const int p1 = perm[m0 + r1]; const int tok1 = (p1 < 0) ? 0 : (p1 >> 1);
  const u16* gA0 = xb + (size_t)tok0 * HID + q0 * 8;
  const u16* gA1 = xb + (size_t)tok1 * HID + q1 * 8;
  const int lA0 = r0 * 64 + (q0 ^ (r0 & 7)) * 8;
  const int lA1 = r1 * 64 + (q1 ^ (r1 & 7)) * 8;

  // B staging: 1024 f32x4 chunks per matrix; thread does 4 (stride 256)
  const float* gB[4]; const float* gU[4]; int lB[4];
  const size_t ebase = (size_t)e * (size_t)(INTER_ * HID);
  #pragma unroll
  for (int i = 0; i < 4; i++) {
    int c = tid + 256 * i;
    int r = c >> 4, q4 = c & 15;
    gB[i] = gw + ebase + (size_t)(n0 + r) * HID + q4 * 4;
    gU[i] = uw + ebase + (size_t)(n0 + r) * HID + q4 * 4;
    lB[i] = r * 64 + (((q4 >> 1) ^ (r & 7)) * 8) + (q4 & 1) * 4;
  }

  const int wm = wv >> 1, wn = wv & 1;
  const int fr = lane & 15, fq = lane >> 4;

  f32x4 accg[2][2], accu[2][2];
  #pragma unroll
  for (int a = 0; a < 2; a++)
    #pragma unroll
    for (int b = 0; b < 2; b++) {
      accg[a][b] = (f32x4){0.f, 0.f, 0.f, 0.f};
      accu[a][b] = (f32x4){0.f, 0.f, 0.f, 0.f};
    }

  for (int kk = 0; kk < HID / 64; kk++) {
    const int k0 = kk * 64;
    // stage A (bf16 passthrough)
    *(u32x4*)&lA[lA0] = *(const u32x4*)(gA0 + k0);
    *(u32x4*)&lA[lA1] = *(const u32x4*)(gA1 + k0);
    // stage B gate/up (f32 -> bf16)
    #pragma unroll
    for (int i = 0; i < 4; i++) {
      f32x4 vg = *(const f32x4*)(gB[i] + k0);
      f32x4 vu = *(const f32x4*)(gU[i] + k0);
      us4 wg = { f2bf(vg[0]), f2bf(vg[1]), f2bf(vg[2]), f2bf(vg[3]) };
      us4 wu = { f2bf(vu[0]), f2bf(vu[1]), f2bf(vu[2]), f2bf(vu[3]) };
      *(us4*)&lBg[lB[i]] = wg;
      *(us4*)&lBu[lB[i]] = wu;
    }
    __syncthreads();
    #pragma unroll
    for (int kk2 = 0; kk2 < 2; kk2++) {
      bf16x8 af[2], bgf[2], buf_[2];
      #pragma unroll
      for (int m2 = 0; m2 < 2; m2++) {
        int r = wm * 32 + m2 * 16 + fr;
        int q = kk2 * 4 + fq;
        af[m2] = *(const bf16x8*)&lA[r * 64 + (q ^ (r & 7)) * 8];
      }
      #pragma unroll
      for (int n2 = 0; n2 < 2; n2++) {
        int r = wn * 32 + n2 * 16 + fr;
        int q = kk2 * 4 + fq;
        bgf[n2]  = *(const bf16x8*)&lBg[r * 64 + (q ^ (r & 7)) * 8];
        buf_[n2] = *(const bf16x8*)&lBu[r * 64 + (q ^ (r & 7)) * 8];
      }
      #pragma unroll
      for (int m2 = 0; m2 < 2; m2++)
        #pragma unroll
        for (int n2 = 0; n2 < 2; n2++) {
          accg[m2][n2] = __builtin_amdgcn_mfma_f32_16x16x32_bf16(af[m2], bgf[n2],  accg[m2][n2], 0, 0, 0);
          accu[m2][n2] = __builtin_amdgcn_mfma_f32_16x16x32_bf16(af[m2], buf_[n2], accu[m2][n2], 0, 0, 0);
        }
    }
    __syncthreads();
  }

  // epilogue: h = silu(g) * u  -> bf16
  #pragma unroll
  for (int m2 = 0; m2 < 2; m2++)
    #pragma unroll
    for (int n2 = 0; n2 < 2; n2++)
      #pragma unroll
      for (int q = 0; q < 4; q++) {
        int row = m0 + wm * 32 + m2 * 16 + fq * 4 + q;
        int col = n0 + wn * 32 + n2 * 16 + fr;
        float g = accg[m2][n2][q];
        float u = accu[m2][n2][q];
        float h = (g / (1.0f + __expf(-g))) * u;
        hbuf[(size_t)row * INTER_ + col] = f2bf(h);
      }
}

// ---- GEMM 2: down, weighted scatter-add into out ----
__global__ __launch_bounds__(256) void k_down(const u16* __restrict__ hbuf,
                                              const float* __restrict__ dw,
                                              const int* __restrict__ hdr,
                                              const int* __restrict__ perm,
                                              const float* __restrict__ rw,
                                              float* __restrict__ out) {
  __shared__ __align__(16) u16 lA[4096];
  __shared__ __align__(16) u16 lB[4096];

  const int tid = threadIdx.x;
  const int lane = tid & 63;
  const int wv = tid >> 6;
  const int n0 = blockIdx.x * 64;
  const int m0 = blockIdx.y * 64;
  const int total = hdr[NEXP];
  if (m0 >= total) return;
  int e = 0;
  #pragma unroll
  for (int k = 1; k < NEXP; k++) if (m0 >= hdr[k]) e = k;

  const int c0 = tid, c1 = 256 + tid;
  const int r0 = c0 >> 3, q0 = c0 & 7;
  const int r1 = c1 >> 3, q1 = c1 & 7;
  const u16* gA0 = hbuf + (size_t)(m0 + r0) * INTER_ + q0 * 8;
  const u16* gA1 = hbuf + (size_t)(m0 + r1) * INTER_ + q1 * 8;
  const int lA0 = r0 * 64 + (q0 ^ (r0 & 7)) * 8;
  const int lA1 = r1 * 64 + (q1 ^ (r1 & 7)) * 8;

  const float* gB[4]; int lBo[4];
  const size_t ebase = (size_t)e * (size_t)(HID * INTER_);
  #pragma unroll
  for (int i = 0; i < 4; i++) {
    int c = tid + 256 * i;
    int r = c >> 4, q4 = c & 15;
    gB[i] = dw + ebase + (size_t)(n0 + r) * INTER_ + q4 * 4;
    lBo[i] = r * 64 + (((q4 >> 1) ^ (r & 7)) * 8) + (q4 & 1) * 4;
  }

  const int wm = wv >> 1, wn = wv & 1;
  const int fr = lane & 15, fq = lane >> 4;

  f32x4 acc[2][2];
  #pragma unroll
  for (int a = 0; a < 2; a++)
    #pragma unroll
    for (int b = 0; b < 2; b++) acc[a][b] = (f32x4){0.f, 0.f, 0.f, 0.f};

  for (int kk = 0; kk < INTER_ / 64; kk++) {
    const int k0 = kk * 64;
    *(u32x4*)&lA[lA0] = *(const u32x4*)(gA0 + k0);
    *(u32x4*)&lA[lA1] = *(const u32x4*)(gA1 + k0);
    #pragma unroll
    for (int i = 0; i < 4; i++) {
      f32x4 vb = *(const f32x4*)(gB[i] + k0);
      us4 wb = { f2bf(vb[0]), f2bf(vb[1]), f2bf(vb[2]), f2bf(vb[3]) };
      *(us4*)&lB[lBo[i]] = wb;
    }
    __syncthreads();
    #pragma unroll
    for (int kk2 = 0; kk2 < 2; kk2++) {
      bf16x8 af[2], bf[2];
      #pragma unroll
      for (int m2 = 0; m2 < 2; m2++) {
        int r = wm * 32 + m2 * 16 + fr;
        int q = kk2 * 4 + fq;
        af[m2] = *(const bf16x8*)&lA[r * 64 + (q ^ (r & 7)) * 8];
      }
      #pragma unroll
      for (int n2 = 0; n2 < 2; n2++) {
        int r = wn * 32 + n2 * 16 + fr;
        int q = kk2 * 4 + fq;
        bf[n2] = *(const bf16x8*)&lB[r * 64 + (q ^ (r & 7)) * 8];
      }
      #pragma unroll
      for (int m2 = 0; m2 < 2; m2++)
        #pragma unroll
        for (int n2 = 0; n2 < 2; n2++)
          acc[m2][n2] = __builtin_amdgcn_mfma_f32_16x16x32_bf16(af[m2], bf[n2], acc[m2][n2], 0, 0, 0);
    }
    __syncthreads();
  }

  // epilogue: out[token] += w * val (atomic; token rows may span blocks)
  #pragma unroll
  for (int m2 = 0; m2 < 2; m2++)
    #pragma unroll
    for (int q = 0; q < 4; q++) {
      int row = m0 + wm * 32 + m2 * 16 + fq * 4 + q;
      int p = perm[row];
      if (p < 0) continue;
      int t = p >> 1;
      float w = rw[p];
      #pragma unroll
      for (int n2 = 0; n2 < 2; n2++) {
        int col = n0 + wn * 32 + n2 * 16 + fr;
        atomicAdd(&out[(size_t)t * HID + col], acc[m2][n2][q] * w);
      }
    }
}

extern "C" void kernel_launch(void* const* d_in, const int* in_sizes, int n_in,
                              void* d_out, int out_size, void* d_ws, size_t ws_size,
                              hipStream_t stream) {
  const float* x   = (const float*)d_in[0];
  const float* rw  = (const float*)d_in[1];
  const int*   sel = (const int*)d_in[2];
  // d_in[3] token_per_expert: unused by the reference math
  const float* gw  = (const float*)d_in[4];
  const float* uw  = (const float*)d_in[5];
  const float* dw  = (const float*)d_in[6];
  float* out = (float*)d_out;

  char* ws = (char*)d_ws;
  int*  hdr  = (int*)ws;                              // seg_base[9]
  int*  perm = (int*)(ws + 1024);                     // PERM_MAX ints
  u16*  xb   = (u16*)(ws + 32768);                    // 2048*1024 bf16 = 4 MiB
  u16*  hbuf = (u16*)(ws + 32768 + 4 * 1024 * 1024);  // 4608*1024 bf16 ~ 9.4 MiB

  k_prep<<<dim3(1024), dim3(256), 0, stream>>>(x, xb, out);
  k_route<<<dim3(1), dim3(256), 0, stream>>>(sel, hdr, perm);
  k_gateup<<<dim3(16, 72), dim3(256), 0, stream>>>(xb, gw, uw, hdr, perm, hbuf);
  k_down<<<dim3(16, 72), dim3(256), 0, stream>>>(hbuf, dw, hdr, perm, rw, out);
}